// Round 1
// baseline (378.480 us; speedup 1.0000x reference)
//
#include <hip/hip_runtime.h>
#include <math.h>

#define IN_F   256
#define OUT_F  128
#define HEADS  4
#define HD     (HEADS * OUT_F)   // 512
#define NEG    0.2f
#define CAP    64                // per-node in-edge capacity (mean deg 16, Poisson; P(>64) ~ 1e-20)

// ---------------- GEMM: H = X @ W  ([N,256] x [256,512]) ----------------
#define TM 128
#define TN 64
#define BK 16

__global__ __launch_bounds__(256) void gemm_xw(const float* __restrict__ X,
                                               const float* __restrict__ W,
                                               float* __restrict__ Hout,
                                               int n_nodes) {
    __shared__ float As[BK][TM];   // transposed: As[k][m]
    __shared__ float Bs[BK][TN];
    const int tid = threadIdx.x;
    const int m0 = blockIdx.y * TM;
    const int n0 = blockIdx.x * TN;
    const int tx = tid & 15;        // 16 col groups * 4 cols
    const int ty = tid >> 4;        // 16 row groups * 8 rows
    const int lr = tid >> 1;        // A-load row 0..127
    const int lq = (tid & 1) * 2;   // A-load k-quad base (0 or 2)
    const int br = tid >> 4;        // B-load k row 0..15
    const int bq = tid & 15;        // B-load n-quad

    float acc[8][4];
#pragma unroll
    for (int i = 0; i < 8; ++i)
#pragma unroll
        for (int j = 0; j < 4; ++j) acc[i][j] = 0.f;

    for (int k0 = 0; k0 < IN_F; k0 += BK) {
        const int gm = m0 + lr;
        float4 a0 = make_float4(0.f, 0.f, 0.f, 0.f), a1 = a0;
        if (gm < n_nodes) {
            a0 = *(const float4*)(X + (size_t)gm * IN_F + k0 + lq * 4);
            a1 = *(const float4*)(X + (size_t)gm * IN_F + k0 + lq * 4 + 4);
        }
        float4 b = *(const float4*)(W + (size_t)(k0 + br) * HD + n0 + bq * 4);
        __syncthreads();
        As[lq * 4 + 0][lr] = a0.x; As[lq * 4 + 1][lr] = a0.y;
        As[lq * 4 + 2][lr] = a0.z; As[lq * 4 + 3][lr] = a0.w;
        As[lq * 4 + 4][lr] = a1.x; As[lq * 4 + 5][lr] = a1.y;
        As[lq * 4 + 6][lr] = a1.z; As[lq * 4 + 7][lr] = a1.w;
        *(float4*)&Bs[br][bq * 4] = b;
        __syncthreads();
#pragma unroll
        for (int kk = 0; kk < BK; ++kk) {
            float4 av0 = *(const float4*)&As[kk][ty * 8];
            float4 av1 = *(const float4*)&As[kk][ty * 8 + 4];
            float4 bv  = *(const float4*)&Bs[kk][tx * 4];
            float a[8] = {av0.x, av0.y, av0.z, av0.w, av1.x, av1.y, av1.z, av1.w};
            float bb[4] = {bv.x, bv.y, bv.z, bv.w};
#pragma unroll
            for (int i = 0; i < 8; ++i)
#pragma unroll
                for (int j = 0; j < 4; ++j) acc[i][j] = fmaf(a[i], bb[j], acc[i][j]);
        }
    }
#pragma unroll
    for (int i = 0; i < 8; ++i) {
        int gm = m0 + ty * 8 + i;
        if (gm < n_nodes) {
            float4 v = make_float4(acc[i][0], acc[i][1], acc[i][2], acc[i][3]);
            *(float4*)(Hout + (size_t)gm * HD + n0 + tx * 4) = v;
        }
    }
}

// --------- a_s[n][h] = <h_row, att_src[h]>, a_d likewise (1 wave/node) ---------
__global__ __launch_bounds__(256) void attn_dots(const float* __restrict__ H,
                                                 const float* __restrict__ att_src,
                                                 const float* __restrict__ att_dst,
                                                 float* __restrict__ a_s,
                                                 float* __restrict__ a_d,
                                                 int n_nodes) {
    const int lane = threadIdx.x & 63;
    const int node = blockIdx.x * 4 + (threadIdx.x >> 6);
    if (node >= n_nodes) return;
    const float* hr = H + (size_t)node * HD;
    float ps[HEADS], pd[HEADS];
#pragma unroll
    for (int hd = 0; hd < HEADS; ++hd) {
        float v0 = hr[hd * OUT_F + lane];
        float v1 = hr[hd * OUT_F + 64 + lane];
        ps[hd] = v0 * att_src[hd * OUT_F + lane] + v1 * att_src[hd * OUT_F + 64 + lane];
        pd[hd] = v0 * att_dst[hd * OUT_F + lane] + v1 * att_dst[hd * OUT_F + 64 + lane];
    }
#pragma unroll
    for (int off = 32; off > 0; off >>= 1) {
#pragma unroll
        for (int hd = 0; hd < HEADS; ++hd) {
            ps[hd] += __shfl_xor(ps[hd], off, 64);
            pd[hd] += __shfl_xor(pd[hd], off, 64);
        }
    }
    if (lane == 0) {
#pragma unroll
        for (int hd = 0; hd < HEADS; ++hd) {
            a_s[node * HEADS + hd] = ps[hd];
            a_d[node * HEADS + hd] = pd[hd];
        }
    }
}

// --------- bucket edges by dst: table[d][r] = src ---------
__global__ __launch_bounds__(256) void build_table(const int* __restrict__ src,
                                                   const int* __restrict__ dst,
                                                   int* __restrict__ cursor,
                                                   int* __restrict__ table,
                                                   int n_edges) {
    int e = blockIdx.x * blockDim.x + threadIdx.x;
    if (e >= n_edges) return;
    int d = dst[e];
    int r = atomicAdd(&cursor[d], 1);
    if (r < CAP) table[(size_t)d * CAP + r] = src[e];
}

// --------- per-dst softmax + weighted aggregation (block = 1 node, 128 ch) ---------
__global__ __launch_bounds__(128) void gat_agg(const float* __restrict__ H,
                                               const float* __restrict__ a_s,
                                               const float* __restrict__ a_d,
                                               const int* __restrict__ cursor,
                                               const int* __restrict__ table,
                                               const float* __restrict__ bias,
                                               float* __restrict__ out) {
    const int n = blockIdx.x;
    const int t = threadIdx.x;
    const float4 ad4  = *(const float4*)(a_d + n * 4);
    const float4 asn4 = *(const float4*)(a_s + n * 4);
    const float ad[4]  = {ad4.x, ad4.y, ad4.z, ad4.w};
    const float asn[4] = {asn4.x, asn4.y, asn4.z, asn4.w};
    int deg = cursor[n];
    if (deg > CAP) deg = CAP;
    const int* row = table + (size_t)n * CAP;

    // pass 1: per-head max over self-loop + in-edges (wave-uniform, no barriers)
    float m[4];
#pragma unroll
    for (int hd = 0; hd < 4; ++hd) {
        float al = asn[hd] + ad[hd];
        m[hd] = al > 0.f ? al : NEG * al;
    }
    for (int e = 0; e < deg; ++e) {
        int s = row[e];
        float4 av = *(const float4*)(a_s + s * 4);
        float as_[4] = {av.x, av.y, av.z, av.w};
#pragma unroll
        for (int hd = 0; hd < 4; ++hd) {
            float al = as_[hd] + ad[hd];
            al = al > 0.f ? al : NEG * al;
            m[hd] = fmaxf(m[hd], al);
        }
    }

    // pass 2: unnormalized weighted sum + denom (self loop first)
    float denom[4], acc[4];
    {
        const float* hr = H + (size_t)n * HD;
#pragma unroll
        for (int hd = 0; hd < 4; ++hd) {
            float al = asn[hd] + ad[hd];
            al = al > 0.f ? al : NEG * al;
            float w = __expf(al - m[hd]);
            denom[hd] = w;
            acc[hd] = w * hr[hd * OUT_F + t];
        }
    }
    for (int e = 0; e < deg; ++e) {
        int s = row[e];
        float4 av = *(const float4*)(a_s + s * 4);
        float as_[4] = {av.x, av.y, av.z, av.w};
        const float* hr = H + (size_t)s * HD;
#pragma unroll
        for (int hd = 0; hd < 4; ++hd) {
            float al = as_[hd] + ad[hd];
            al = al > 0.f ? al : NEG * al;
            float w = __expf(al - m[hd]);
            denom[hd] += w;
            acc[hd] = fmaf(w, hr[hd * OUT_F + t], acc[hd]);
        }
    }

    float o = 0.f;
#pragma unroll
    for (int hd = 0; hd < 4; ++hd) o += acc[hd] / denom[hd];
    o = 0.25f * o + bias[t];
    out[(size_t)n * OUT_F + t] = tanhf(o);
}

extern "C" void kernel_launch(void* const* d_in, const int* in_sizes, int n_in,
                              void* d_out, int out_size, void* d_ws, size_t ws_size,
                              hipStream_t stream) {
    const float* x       = (const float*)d_in[0];
    const int*   ei      = (const int*)d_in[1];
    const float* W       = (const float*)d_in[2];
    const float* att_src = (const float*)d_in[3];
    const float* att_dst = (const float*)d_in[4];
    const float* bias    = (const float*)d_in[5];
    float* out = (float*)d_out;

    const int n_nodes = in_sizes[0] / IN_F;     // 30000
    const int n_edges = in_sizes[1] / 2;        // 480000
    const int* src = ei;
    const int* dst = ei + n_edges;

    char* ws = (char*)d_ws;
    size_t off = 0;
    auto alloc = [&](size_t bytes) -> void* {
        void* p = ws + off;
        off = (off + bytes + 255) & ~(size_t)255;
        return p;
    };
    float* H      = (float*)alloc((size_t)n_nodes * HD * sizeof(float));   // 61.4 MB
    float* a_s    = (float*)alloc((size_t)n_nodes * HEADS * sizeof(float));
    float* a_d    = (float*)alloc((size_t)n_nodes * HEADS * sizeof(float));
    int*   cursor = (int*)alloc((size_t)n_nodes * sizeof(int));
    int*   table  = (int*)alloc((size_t)n_nodes * CAP * sizeof(int));      // 7.7 MB
    (void)ws_size; (void)n_in; (void)out_size;

    hipMemsetAsync(cursor, 0, (size_t)n_nodes * sizeof(int), stream);

    dim3 ggrid(HD / TN, (n_nodes + TM - 1) / TM);
    gemm_xw<<<ggrid, 256, 0, stream>>>(x, W, H, n_nodes);
    build_table<<<(n_edges + 255) / 256, 256, 0, stream>>>(src, dst, cursor, table, n_edges);
    attn_dots<<<(n_nodes + 3) / 4, 256, 0, stream>>>(H, att_src, att_dst, a_s, a_d, n_nodes);
    gat_agg<<<n_nodes, 128, 0, stream>>>(H, a_s, a_d, cursor, table, bias, out);
}

// Round 2
// 322.260 us; speedup vs baseline: 1.1745x; 1.1745x over previous
//
#include <hip/hip_runtime.h>
#include <math.h>

#define IN_F   256
#define OUT_F  128
#define HEADS  4
#define HD     (HEADS * OUT_F)   // 512
#define NEG    0.2f
#define CAP    64                // per-node in-edge capacity (mean deg 16; P(deg>64) ~ 1e-18)

typedef __attribute__((ext_vector_type(8))) short short8;   // 8 bf16 = 4 VGPRs
typedef __attribute__((ext_vector_type(4))) float f32x4;

static __device__ __forceinline__ ushort f2bf(float f) {
    union { float f; unsigned u; } v; v.f = f;
    unsigned r = (v.u + 0x7FFFu + ((v.u >> 16) & 1u)) >> 16;   // RNE
    return (ushort)r;
}

// ---------------- X [N,256] f32 -> Xb bf16 ----------------
__global__ __launch_bounds__(256) void cvt_x(const float* __restrict__ X,
                                             ushort* __restrict__ Xb, int total4) {
    int i = blockIdx.x * blockDim.x + threadIdx.x;
    if (i >= total4) return;
    float4 v = ((const float4*)X)[i];
    ushort4 o; o.x = f2bf(v.x); o.y = f2bf(v.y); o.z = f2bf(v.z); o.w = f2bf(v.w);
    ((ushort4*)Xb)[i] = o;
}

// ---------------- W [256][512] f32 -> WT [512][256] bf16 ----------------
__global__ __launch_bounds__(256) void cvt_wt(const float* __restrict__ W,
                                              ushort* __restrict__ WT) {
    int idx = blockIdx.x * blockDim.x + threadIdx.x;   // 512*256
    int n = idx >> 8, k = idx & 255;
    WT[idx] = f2bf(W[k * HD + n]);
}

// ---------------- H = Xb @ WT^T via bf16 MFMA ----------------
// block tile 128x128, 4 waves, each wave 64x64 (4x4 frags of 16x16), BK=32
#define GBM 128
#define GBN 128
#define GBK 32
#define LDA 40   // padded LDS row (ushorts): 32 + 8 -> stride 20 banks, conflict-free-ish

__global__ __launch_bounds__(256) void gemm_mfma(const ushort* __restrict__ Xb,
                                                 const ushort* __restrict__ WT,
                                                 float* __restrict__ Hout,
                                                 int n_nodes) {
    __shared__ ushort As[GBM][LDA];
    __shared__ ushort Bs[GBN][LDA];
    const int tid = threadIdx.x;
    const int m0 = blockIdx.y * GBM;
    const int n0 = blockIdx.x * GBN;
    const int wave = tid >> 6, lane = tid & 63;
    const int wm = (wave & 1) * 64, wn = (wave >> 1) * 64;
    const int l15 = lane & 15, quad = lane >> 4;

    f32x4 acc[4][4];
#pragma unroll
    for (int i = 0; i < 4; ++i)
#pragma unroll
        for (int j = 0; j < 4; ++j) acc[i][j] = (f32x4){0.f, 0.f, 0.f, 0.f};

    const int r = tid >> 2, q = tid & 3;   // staging: 2 chunks of 16B per thread per tile

    for (int k0 = 0; k0 < IN_F; k0 += GBK) {
        uint4 a0 = make_uint4(0, 0, 0, 0), a1 = a0;
        int gm0 = m0 + r, gm1 = m0 + 64 + r;
        if (gm0 < n_nodes) a0 = *(const uint4*)(Xb + (size_t)gm0 * IN_F + k0 + q * 8);
        if (gm1 < n_nodes) a1 = *(const uint4*)(Xb + (size_t)gm1 * IN_F + k0 + q * 8);
        uint4 b0 = *(const uint4*)(WT + (size_t)(n0 + r) * IN_F + k0 + q * 8);
        uint4 b1 = *(const uint4*)(WT + (size_t)(n0 + 64 + r) * IN_F + k0 + q * 8);
        __syncthreads();
        *(uint4*)&As[r][q * 8] = a0;
        *(uint4*)&As[64 + r][q * 8] = a1;
        *(uint4*)&Bs[r][q * 8] = b0;
        *(uint4*)&Bs[64 + r][q * 8] = b1;
        __syncthreads();

        short8 af[4], bf_[4];
#pragma unroll
        for (int f = 0; f < 4; ++f) {
            af[f]  = *(const short8*)&As[wm + f * 16 + l15][quad * 8];
            bf_[f] = *(const short8*)&Bs[wn + f * 16 + l15][quad * 8];
        }
#pragma unroll
        for (int fm = 0; fm < 4; ++fm)
#pragma unroll
            for (int fn = 0; fn < 4; ++fn)
                acc[fm][fn] = __builtin_amdgcn_mfma_f32_16x16x32_bf16(
                    af[fm], bf_[fn], acc[fm][fn], 0, 0, 0);
    }

#pragma unroll
    for (int fm = 0; fm < 4; ++fm) {
        int gmb = m0 + wm + fm * 16 + quad * 4;
#pragma unroll
        for (int reg = 0; reg < 4; ++reg) {
            int gm = gmb + reg;
            if (gm < n_nodes) {
#pragma unroll
                for (int fn = 0; fn < 4; ++fn)
                    Hout[(size_t)gm * HD + n0 + wn + fn * 16 + l15] = acc[fm][fn][reg];
            }
        }
    }
}

// --------- a_s[n][h] = <h_row, att_src[h]>, a_d likewise (1 wave/node) ---------
__global__ __launch_bounds__(256) void attn_dots(const float* __restrict__ H,
                                                 const float* __restrict__ att_src,
                                                 const float* __restrict__ att_dst,
                                                 float* __restrict__ a_s,
                                                 float* __restrict__ a_d,
                                                 int n_nodes) {
    const int lane = threadIdx.x & 63;
    const int node = blockIdx.x * 4 + (threadIdx.x >> 6);
    if (node >= n_nodes) return;
    const float* hr = H + (size_t)node * HD;
    float ps[HEADS], pd[HEADS];
#pragma unroll
    for (int hd = 0; hd < HEADS; ++hd) {
        float v0 = hr[hd * OUT_F + lane];
        float v1 = hr[hd * OUT_F + 64 + lane];
        ps[hd] = v0 * att_src[hd * OUT_F + lane] + v1 * att_src[hd * OUT_F + 64 + lane];
        pd[hd] = v0 * att_dst[hd * OUT_F + lane] + v1 * att_dst[hd * OUT_F + 64 + lane];
    }
#pragma unroll
    for (int off = 32; off > 0; off >>= 1) {
#pragma unroll
        for (int hd = 0; hd < HEADS; ++hd) {
            ps[hd] += __shfl_xor(ps[hd], off, 64);
            pd[hd] += __shfl_xor(pd[hd], off, 64);
        }
    }
    if (lane == 0) {
#pragma unroll
        for (int hd = 0; hd < HEADS; ++hd) {
            a_s[node * HEADS + hd] = ps[hd];
            a_d[node * HEADS + hd] = pd[hd];
        }
    }
}

// --------- bucket edges by dst: table[d][r] = src ---------
__global__ __launch_bounds__(256) void build_table(const int* __restrict__ src,
                                                   const int* __restrict__ dst,
                                                   int* __restrict__ cursor,
                                                   int* __restrict__ table,
                                                   int n_edges) {
    int e = blockIdx.x * blockDim.x + threadIdx.x;
    if (e >= n_edges) return;
    int d = dst[e];
    int r = atomicAdd(&cursor[d], 1);
    if (r < CAP) table[(size_t)d * CAP + r] = src[e];
}

// --------- softmax prep: 1 thread/node -> wtab (exp), wself, rden=1/denom ---------
__global__ __launch_bounds__(256) void prep_weights(const float* __restrict__ a_s,
                                                    const float* __restrict__ a_d,
                                                    const int* __restrict__ cursor,
                                                    const int* __restrict__ table,
                                                    float* __restrict__ wtab,
                                                    float* __restrict__ wself,
                                                    float* __restrict__ rden,
                                                    int n_nodes) {
    int n = blockIdx.x * blockDim.x + threadIdx.x;
    if (n >= n_nodes) return;
    const float4 ad4 = *(const float4*)(a_d + n * 4);
    const float4 as4 = *(const float4*)(a_s + n * 4);
    const float ad[4] = {ad4.x, ad4.y, ad4.z, ad4.w};
    int deg = cursor[n]; if (deg > CAP) deg = CAP;
    const int* row = table + (size_t)n * CAP;

    float m[4], aself[4];
    {
        const float asn[4] = {as4.x, as4.y, as4.z, as4.w};
#pragma unroll
        for (int hd = 0; hd < 4; ++hd) {
            float al = asn[hd] + ad[hd];
            aself[hd] = al > 0.f ? al : NEG * al;
            m[hd] = aself[hd];
        }
    }
    for (int e = 0; e < deg; ++e) {
        int s = row[e];
        float4 av = *(const float4*)(a_s + s * 4);
        float as_[4] = {av.x, av.y, av.z, av.w};
#pragma unroll
        for (int hd = 0; hd < 4; ++hd) {
            float al = as_[hd] + ad[hd];
            al = al > 0.f ? al : NEG * al;
            m[hd] = fmaxf(m[hd], al);
        }
    }
    float den[4];
    {
        float4 wo;
        float* w = (float*)&wo;
#pragma unroll
        for (int hd = 0; hd < 4; ++hd) { w[hd] = __expf(aself[hd] - m[hd]); den[hd] = w[hd]; }
        *(float4*)(wself + n * 4) = wo;
    }
    for (int e = 0; e < deg; ++e) {
        int s = row[e];
        float4 av = *(const float4*)(a_s + s * 4);
        float as_[4] = {av.x, av.y, av.z, av.w};
        float4 wo;
        float* w = (float*)&wo;
#pragma unroll
        for (int hd = 0; hd < 4; ++hd) {
            float al = as_[hd] + ad[hd];
            al = al > 0.f ? al : NEG * al;
            w[hd] = __expf(al - m[hd]);
            den[hd] += w[hd];
        }
        *(float4*)(wtab + ((size_t)n * CAP + e) * 4) = wo;
    }
    float4 rd;
    rd.x = 1.f / den[0]; rd.y = 1.f / den[1]; rd.z = 1.f / den[2]; rd.w = 1.f / den[3];
    *(float4*)(rden + n * 4) = rd;
}

// --------- aggregation: block = 1 node, 128 channels; weights precomputed ---------
__global__ __launch_bounds__(128) void gat_agg(const float* __restrict__ H,
                                               const float* __restrict__ wtab,
                                               const float* __restrict__ wself,
                                               const float* __restrict__ rden,
                                               const int* __restrict__ cursor,
                                               const int* __restrict__ table,
                                               const float* __restrict__ bias,
                                               float* __restrict__ out) {
    const int n = blockIdx.x;
    const int t = threadIdx.x;
    int deg = cursor[n]; if (deg > CAP) deg = CAP;
    const int* row = table + (size_t)n * CAP;
    const float* wrow = wtab + (size_t)n * CAP * 4;

    float acc[4];
    {
        const float4 ws = *(const float4*)(wself + n * 4);
        const float* hr = H + (size_t)n * HD;
        acc[0] = ws.x * hr[0 * OUT_F + t];
        acc[1] = ws.y * hr[1 * OUT_F + t];
        acc[2] = ws.z * hr[2 * OUT_F + t];
        acc[3] = ws.w * hr[3 * OUT_F + t];
    }
    for (int e = 0; e < deg; ++e) {
        int s = row[e];
        float4 w = *(const float4*)(wrow + e * 4);
        const float* hr = H + (size_t)s * HD;
        acc[0] = fmaf(w.x, hr[0 * OUT_F + t], acc[0]);
        acc[1] = fmaf(w.y, hr[1 * OUT_F + t], acc[1]);
        acc[2] = fmaf(w.z, hr[2 * OUT_F + t], acc[2]);
        acc[3] = fmaf(w.w, hr[3 * OUT_F + t], acc[3]);
    }
    const float4 rd = *(const float4*)(rden + n * 4);
    float o = acc[0] * rd.x + acc[1] * rd.y + acc[2] * rd.z + acc[3] * rd.w;
    o = 0.25f * o + bias[t];
    out[(size_t)n * OUT_F + t] = tanhf(o);
}

extern "C" void kernel_launch(void* const* d_in, const int* in_sizes, int n_in,
                              void* d_out, int out_size, void* d_ws, size_t ws_size,
                              hipStream_t stream) {
    const float* x       = (const float*)d_in[0];
    const int*   ei      = (const int*)d_in[1];
    const float* W       = (const float*)d_in[2];
    const float* att_src = (const float*)d_in[3];
    const float* att_dst = (const float*)d_in[4];
    const float* bias    = (const float*)d_in[5];
    float* out = (float*)d_out;

    const int n_nodes = in_sizes[0] / IN_F;     // 30000
    const int n_edges = in_sizes[1] / 2;        // 480000
    const int* src = ei;
    const int* dst = ei + n_edges;

    char* ws = (char*)d_ws;
    size_t off = 0;
    auto alloc = [&](size_t bytes) -> void* {
        void* p = ws + off;
        off = (off + bytes + 255) & ~(size_t)255;
        return p;
    };
    float*  H      = (float*)alloc((size_t)n_nodes * HD * sizeof(float));       // 61.4 MB
    ushort* Xb     = (ushort*)alloc((size_t)n_nodes * IN_F * sizeof(ushort));   // 15.4 MB
    ushort* WT     = (ushort*)alloc((size_t)HD * IN_F * sizeof(ushort));        // 0.26 MB
    float*  a_s    = (float*)alloc((size_t)n_nodes * HEADS * sizeof(float));
    float*  a_d    = (float*)alloc((size_t)n_nodes * HEADS * sizeof(float));
    int*    cursor = (int*)alloc((size_t)n_nodes * sizeof(int));
    int*    table  = (int*)alloc((size_t)n_nodes * CAP * sizeof(int));          // 7.7 MB
    float*  wtab   = (float*)alloc((size_t)n_nodes * CAP * 4 * sizeof(float));  // 30.7 MB
    float*  wself  = (float*)alloc((size_t)n_nodes * 4 * sizeof(float));
    float*  rden   = (float*)alloc((size_t)n_nodes * 4 * sizeof(float));
    (void)ws_size; (void)n_in; (void)out_size;

    hipMemsetAsync(cursor, 0, (size_t)n_nodes * sizeof(int), stream);

    int total4 = n_nodes * IN_F / 4;
    cvt_x<<<(total4 + 255) / 256, 256, 0, stream>>>(x, Xb, total4);
    cvt_wt<<<(HD * IN_F) / 256, 256, 0, stream>>>(W, WT);
    build_table<<<(n_edges + 255) / 256, 256, 0, stream>>>(src, dst, cursor, table, n_edges);

    dim3 ggrid(HD / GBN, (n_nodes + GBM - 1) / GBM);   // 4 x 235
    gemm_mfma<<<ggrid, 256, 0, stream>>>(Xb, WT, H, n_nodes);

    attn_dots<<<(n_nodes + 3) / 4, 256, 0, stream>>>(H, att_src, att_dst, a_s, a_d, n_nodes);
    prep_weights<<<(n_nodes + 255) / 256, 256, 0, stream>>>(a_s, a_d, cursor, table,
                                                            wtab, wself, rden, n_nodes);
    gat_agg<<<n_nodes, 128, 0, stream>>>(H, wtab, wself, rden, cursor, table, bias, out);
}

// Round 3
// 235.691 us; speedup vs baseline: 1.6058x; 1.3673x over previous
//
#include <hip/hip_runtime.h>
#include <math.h>

#define IN_F   256
#define OUT_F  128
#define HEADS  4
#define HD     (HEADS * OUT_F)   // 512
#define NEG    0.2f
#define CAP    64                // per-node in-edge capacity (mean deg 16; P(deg>64) ~ 1e-18)

typedef __attribute__((ext_vector_type(8))) short short8;   // 8 bf16 = 4 VGPRs
typedef __attribute__((ext_vector_type(4))) float f32x4;

static __device__ __forceinline__ ushort f2bf(float f) {
    union { float f; unsigned u; } v; v.f = f;
    unsigned r = (v.u + 0x7FFFu + ((v.u >> 16) & 1u)) >> 16;   // RNE
    return (ushort)r;
}
static __device__ __forceinline__ float bflo(unsigned u) {
    union { unsigned u; float f; } v; v.u = u << 16; return v.f;
}
static __device__ __forceinline__ float bfhi(unsigned u) {
    union { unsigned u; float f; } v; v.u = u & 0xFFFF0000u; return v.f;
}

// ---------------- WT bf16 [512][256] + va = W @ att  (fp32 [4][256] x2) ----------------
__global__ __launch_bounds__(256) void cvt_wt(const float* __restrict__ W,
                                              ushort* __restrict__ WT) {
    int idx = blockIdx.x * blockDim.x + threadIdx.x;   // 512*256
    int n = idx >> 8, k = idx & 255;
    WT[idx] = f2bf(W[k * HD + n]);
}
__global__ __launch_bounds__(256) void calc_va(const float* __restrict__ W,
                                               const float* __restrict__ att_src,
                                               const float* __restrict__ att_dst,
                                               float* __restrict__ va_s,
                                               float* __restrict__ va_d) {
    int idx = blockIdx.x * blockDim.x + threadIdx.x;   // 4*256
    int h = idx >> 8, k = idx & 255;
    const float* wr = W + (size_t)k * HD + h * OUT_F;
    const float* as = att_src + h * OUT_F;
    const float* ad = att_dst + h * OUT_F;
    float ss = 0.f, sd = 0.f;
#pragma unroll 8
    for (int c = 0; c < OUT_F; ++c) {
        float w = wr[c];
        ss = fmaf(w, as[c], ss);
        sd = fmaf(w, ad[c], sd);
    }
    va_s[idx] = ss;
    va_d[idx] = sd;
}

// ------- fused: X f32 -> Xb bf16, plus a_s/a_d = x . va (wave per node) -------
__global__ __launch_bounds__(256) void fused_x(const float* __restrict__ X,
                                               const float* __restrict__ va_s,
                                               const float* __restrict__ va_d,
                                               ushort* __restrict__ Xb,
                                               float* __restrict__ a_s,
                                               float* __restrict__ a_d,
                                               int n_nodes) {
    const int lane = threadIdx.x & 63;
    const int node = blockIdx.x * 4 + (threadIdx.x >> 6);
    if (node >= n_nodes) return;
    float4 v = *(const float4*)(X + (size_t)node * IN_F + lane * 4);
    ushort4 o; o.x = f2bf(v.x); o.y = f2bf(v.y); o.z = f2bf(v.z); o.w = f2bf(v.w);
    *(ushort4*)(Xb + (size_t)node * IN_F + lane * 4) = o;

    float ps[HEADS], pd[HEADS];
#pragma unroll
    for (int hd = 0; hd < HEADS; ++hd) {
        float4 s4 = *(const float4*)(va_s + hd * IN_F + lane * 4);
        float4 d4 = *(const float4*)(va_d + hd * IN_F + lane * 4);
        ps[hd] = v.x * s4.x + v.y * s4.y + v.z * s4.z + v.w * s4.w;
        pd[hd] = v.x * d4.x + v.y * d4.y + v.z * d4.z + v.w * d4.w;
    }
#pragma unroll
    for (int off = 32; off > 0; off >>= 1) {
#pragma unroll
        for (int hd = 0; hd < HEADS; ++hd) {
            ps[hd] += __shfl_xor(ps[hd], off, 64);
            pd[hd] += __shfl_xor(pd[hd], off, 64);
        }
    }
    if (lane == 0) {
        float4 s4 = make_float4(ps[0], ps[1], ps[2], ps[3]);
        float4 d4 = make_float4(pd[0], pd[1], pd[2], pd[3]);
        *(float4*)(a_s + node * 4) = s4;
        *(float4*)(a_d + node * 4) = d4;
    }
}

// ---------------- Hb(bf16) = Xb @ WT^T via bf16 MFMA ----------------
#define GBM 128
#define GBN 128
#define GBK 32
#define LDA 40

__global__ __launch_bounds__(256) void gemm_mfma(const ushort* __restrict__ Xb,
                                                 const ushort* __restrict__ WT,
                                                 ushort* __restrict__ Hb,
                                                 int n_nodes) {
    __shared__ ushort As[GBM][LDA];
    __shared__ ushort Bs[GBN][LDA];
    const int tid = threadIdx.x;
    const int m0 = blockIdx.y * GBM;
    const int n0 = blockIdx.x * GBN;
    const int wave = tid >> 6, lane = tid & 63;
    const int wm = (wave & 1) * 64, wn = (wave >> 1) * 64;
    const int l15 = lane & 15, quad = lane >> 4;

    f32x4 acc[4][4];
#pragma unroll
    for (int i = 0; i < 4; ++i)
#pragma unroll
        for (int j = 0; j < 4; ++j) acc[i][j] = (f32x4){0.f, 0.f, 0.f, 0.f};

    const int r = tid >> 2, q = tid & 3;

    for (int k0 = 0; k0 < IN_F; k0 += GBK) {
        uint4 a0 = make_uint4(0, 0, 0, 0), a1 = a0;
        int gm0 = m0 + r, gm1 = m0 + 64 + r;
        if (gm0 < n_nodes) a0 = *(const uint4*)(Xb + (size_t)gm0 * IN_F + k0 + q * 8);
        if (gm1 < n_nodes) a1 = *(const uint4*)(Xb + (size_t)gm1 * IN_F + k0 + q * 8);
        uint4 b0 = *(const uint4*)(WT + (size_t)(n0 + r) * IN_F + k0 + q * 8);
        uint4 b1 = *(const uint4*)(WT + (size_t)(n0 + 64 + r) * IN_F + k0 + q * 8);
        __syncthreads();
        *(uint4*)&As[r][q * 8] = a0;
        *(uint4*)&As[64 + r][q * 8] = a1;
        *(uint4*)&Bs[r][q * 8] = b0;
        *(uint4*)&Bs[64 + r][q * 8] = b1;
        __syncthreads();

        short8 af[4], bf_[4];
#pragma unroll
        for (int f = 0; f < 4; ++f) {
            af[f]  = *(const short8*)&As[wm + f * 16 + l15][quad * 8];
            bf_[f] = *(const short8*)&Bs[wn + f * 16 + l15][quad * 8];
        }
#pragma unroll
        for (int fm = 0; fm < 4; ++fm)
#pragma unroll
            for (int fn = 0; fn < 4; ++fn)
                acc[fm][fn] = __builtin_amdgcn_mfma_f32_16x16x32_bf16(
                    af[fm], bf_[fn], acc[fm][fn], 0, 0, 0);
    }

#pragma unroll
    for (int fm = 0; fm < 4; ++fm) {
        int gmb = m0 + wm + fm * 16 + quad * 4;
#pragma unroll
        for (int reg = 0; reg < 4; ++reg) {
            int gm = gmb + reg;
            if (gm < n_nodes) {
#pragma unroll
                for (int fn = 0; fn < 4; ++fn)
                    Hb[(size_t)gm * HD + n0 + wn + fn * 16 + l15] =
                        f2bf(acc[fm][fn][reg]);
            }
        }
    }
}

// --------- bucket edges by dst: table[d][r] = src ---------
__global__ __launch_bounds__(256) void build_table(const int* __restrict__ src,
                                                   const int* __restrict__ dst,
                                                   int* __restrict__ cursor,
                                                   int* __restrict__ table,
                                                   int n_edges) {
    int e = blockIdx.x * blockDim.x + threadIdx.x;
    if (e >= n_edges) return;
    int d = dst[e];
    int r = atomicAdd(&cursor[d], 1);
    if (r < CAP) table[(size_t)d * CAP + r] = src[e];
}

// --------- softmax prep: wave per node, lane per edge slot ---------
__global__ __launch_bounds__(256) void prep_weights(const float* __restrict__ a_s,
                                                    const float* __restrict__ a_d,
                                                    const int* __restrict__ cursor,
                                                    const int* __restrict__ table,
                                                    float* __restrict__ wtab,
                                                    float* __restrict__ wself,
                                                    float* __restrict__ rden,
                                                    int n_nodes) {
    const int lane = threadIdx.x & 63;
    const int n = blockIdx.x * 4 + (threadIdx.x >> 6);
    if (n >= n_nodes) return;
    int deg = cursor[n]; if (deg > CAP) deg = CAP;
    const int* row = table + (size_t)n * CAP;
    const float4 ad4 = *(const float4*)(a_d + n * 4);
    const float4 as4 = *(const float4*)(a_s + n * 4);
    const float ad[4] = {ad4.x, ad4.y, ad4.z, ad4.w};

    float aself[4];
    {
        const float asn[4] = {as4.x, as4.y, as4.z, as4.w};
#pragma unroll
        for (int hd = 0; hd < 4; ++hd) {
            float al = asn[hd] + ad[hd];
            aself[hd] = al > 0.f ? al : NEG * al;
        }
    }
    const bool act = lane < deg;
    float al[4];
    {
        int s = act ? row[lane] : 0;
        float4 av = act ? *(const float4*)(a_s + s * 4) : make_float4(0.f, 0.f, 0.f, 0.f);
        const float as_[4] = {av.x, av.y, av.z, av.w};
#pragma unroll
        for (int hd = 0; hd < 4; ++hd) {
            float a = as_[hd] + ad[hd];
            a = a > 0.f ? a : NEG * a;
            al[hd] = act ? a : -1e30f;
        }
    }
    float m[4];
#pragma unroll
    for (int hd = 0; hd < 4; ++hd) m[hd] = al[hd];
#pragma unroll
    for (int off = 32; off > 0; off >>= 1)
#pragma unroll
        for (int hd = 0; hd < 4; ++hd)
            m[hd] = fmaxf(m[hd], __shfl_xor(m[hd], off, 64));
#pragma unroll
    for (int hd = 0; hd < 4; ++hd) m[hd] = fmaxf(m[hd], aself[hd]);

    float w[4], den[4];
#pragma unroll
    for (int hd = 0; hd < 4; ++hd) {
        w[hd] = act ? __expf(al[hd] - m[hd]) : 0.f;
        den[hd] = w[hd];
    }
#pragma unroll
    for (int off = 32; off > 0; off >>= 1)
#pragma unroll
        for (int hd = 0; hd < 4; ++hd)
            den[hd] += __shfl_xor(den[hd], off, 64);

    if (act)
        *(float4*)(wtab + ((size_t)n * CAP + lane) * 4) =
            make_float4(w[0], w[1], w[2], w[3]);
    if (lane == 0) {
        float es[4];
        float4 ws, rd;
#pragma unroll
        for (int hd = 0; hd < 4; ++hd) es[hd] = __expf(aself[hd] - m[hd]);
        ws = make_float4(es[0], es[1], es[2], es[3]);
        rd = make_float4(1.f / (den[0] + es[0]), 1.f / (den[1] + es[1]),
                         1.f / (den[2] + es[2]), 1.f / (den[3] + es[3]));
        *(float4*)(wself + n * 4) = ws;
        *(float4*)(rden + n * 4) = rd;
    }
}

// --------- aggregation: wave per node; lane owns 2 channels x 4 heads ---------
__global__ __launch_bounds__(256) void gat_agg(const ushort* __restrict__ Hb,
                                               const float* __restrict__ wtab,
                                               const float* __restrict__ wself,
                                               const float* __restrict__ rden,
                                               const int* __restrict__ cursor,
                                               const int* __restrict__ table,
                                               const float* __restrict__ bias,
                                               float* __restrict__ out) {
    const int lane = threadIdx.x & 63;
    const int n = blockIdx.x * 4 + (threadIdx.x >> 6);
    if (n >= 30000) return;
    int deg = cursor[n]; if (deg > CAP) deg = CAP;
    const int* row = table + (size_t)n * CAP;
    const float* wrow = wtab + (size_t)n * CAP * 4;
    const unsigned* hbase = (const unsigned*)Hb;

    float acc0[4], acc1[4];
    {
        const float4 ws = *(const float4*)(wself + n * 4);
        const float wsv[4] = {ws.x, ws.y, ws.z, ws.w};
        const unsigned* p = hbase + (size_t)n * 256;
#pragma unroll
        for (int hd = 0; hd < 4; ++hd) {
            unsigned u = p[hd * 64 + lane];
            acc0[hd] = wsv[hd] * bflo(u);
            acc1[hd] = wsv[hd] * bfhi(u);
        }
    }
    int e = 0;
    for (; e + 4 <= deg; e += 4) {
        int4 r4 = *(const int4*)(row + e);
        float4 w0 = *(const float4*)(wrow + (e + 0) * 4);
        float4 w1 = *(const float4*)(wrow + (e + 1) * 4);
        float4 w2 = *(const float4*)(wrow + (e + 2) * 4);
        float4 w3 = *(const float4*)(wrow + (e + 3) * 4);
        const unsigned* p0 = hbase + (size_t)r4.x * 256;
        const unsigned* p1 = hbase + (size_t)r4.y * 256;
        const unsigned* p2 = hbase + (size_t)r4.z * 256;
        const unsigned* p3 = hbase + (size_t)r4.w * 256;
        unsigned u0[4], u1[4], u2[4], u3[4];
#pragma unroll
        for (int hd = 0; hd < 4; ++hd) {
            u0[hd] = p0[hd * 64 + lane];
            u1[hd] = p1[hd * 64 + lane];
            u2[hd] = p2[hd * 64 + lane];
            u3[hd] = p3[hd * 64 + lane];
        }
        const float wv0[4] = {w0.x, w0.y, w0.z, w0.w};
        const float wv1[4] = {w1.x, w1.y, w1.z, w1.w};
        const float wv2[4] = {w2.x, w2.y, w2.z, w2.w};
        const float wv3[4] = {w3.x, w3.y, w3.z, w3.w};
#pragma unroll
        for (int hd = 0; hd < 4; ++hd) {
            acc0[hd] = fmaf(wv0[hd], bflo(u0[hd]), acc0[hd]);
            acc1[hd] = fmaf(wv0[hd], bfhi(u0[hd]), acc1[hd]);
            acc0[hd] = fmaf(wv1[hd], bflo(u1[hd]), acc0[hd]);
            acc1[hd] = fmaf(wv1[hd], bfhi(u1[hd]), acc1[hd]);
            acc0[hd] = fmaf(wv2[hd], bflo(u2[hd]), acc0[hd]);
            acc1[hd] = fmaf(wv2[hd], bfhi(u2[hd]), acc1[hd]);
            acc0[hd] = fmaf(wv3[hd], bflo(u3[hd]), acc0[hd]);
            acc1[hd] = fmaf(wv3[hd], bfhi(u3[hd]), acc1[hd]);
        }
    }
    for (; e < deg; ++e) {
        int s = row[e];
        float4 w = *(const float4*)(wrow + e * 4);
        const float wv[4] = {w.x, w.y, w.z, w.w};
        const unsigned* p = hbase + (size_t)s * 256;
#pragma unroll
        for (int hd = 0; hd < 4; ++hd) {
            unsigned u = p[hd * 64 + lane];
            acc0[hd] = fmaf(wv[hd], bflo(u), acc0[hd]);
            acc1[hd] = fmaf(wv[hd], bfhi(u), acc1[hd]);
        }
    }
    const float4 rd = *(const float4*)(rden + n * 4);
    const float rdv[4] = {rd.x, rd.y, rd.z, rd.w};
    float o0 = 0.f, o1 = 0.f;
#pragma unroll
    for (int hd = 0; hd < 4; ++hd) {
        o0 = fmaf(acc0[hd], rdv[hd], o0);
        o1 = fmaf(acc1[hd], rdv[hd], o1);
    }
    float2 b = *(const float2*)(bias + 2 * lane);
    o0 = 0.25f * o0 + b.x;
    o1 = 0.25f * o1 + b.y;
    float2 ov = make_float2(tanhf(o0), tanhf(o1));
    *(float2*)(out + (size_t)n * OUT_F + 2 * lane) = ov;
}

extern "C" void kernel_launch(void* const* d_in, const int* in_sizes, int n_in,
                              void* d_out, int out_size, void* d_ws, size_t ws_size,
                              hipStream_t stream) {
    const float* x       = (const float*)d_in[0];
    const int*   ei      = (const int*)d_in[1];
    const float* W       = (const float*)d_in[2];
    const float* att_src = (const float*)d_in[3];
    const float* att_dst = (const float*)d_in[4];
    const float* bias    = (const float*)d_in[5];
    float* out = (float*)d_out;

    const int n_nodes = in_sizes[0] / IN_F;     // 30000
    const int n_edges = in_sizes[1] / 2;        // 480000
    const int* src = ei;
    const int* dst = ei + n_edges;

    char* ws = (char*)d_ws;
    size_t off = 0;
    auto alloc = [&](size_t bytes) -> void* {
        void* p = ws + off;
        off = (off + bytes + 255) & ~(size_t)255;
        return p;
    };
    ushort* Hb     = (ushort*)alloc((size_t)n_nodes * HD * sizeof(ushort));     // 30.7 MB
    ushort* Xb     = (ushort*)alloc((size_t)n_nodes * IN_F * sizeof(ushort));   // 15.4 MB
    ushort* WT     = (ushort*)alloc((size_t)HD * IN_F * sizeof(ushort));        // 0.26 MB
    float*  va_s   = (float*)alloc((size_t)HEADS * IN_F * sizeof(float));
    float*  va_d   = (float*)alloc((size_t)HEADS * IN_F * sizeof(float));
    float*  a_s    = (float*)alloc((size_t)n_nodes * HEADS * sizeof(float));
    float*  a_d    = (float*)alloc((size_t)n_nodes * HEADS * sizeof(float));
    int*    cursor = (int*)alloc((size_t)n_nodes * sizeof(int));
    int*    table  = (int*)alloc((size_t)n_nodes * CAP * sizeof(int));          // 7.7 MB
    float*  wtab   = (float*)alloc((size_t)n_nodes * CAP * 4 * sizeof(float));  // 30.7 MB
    float*  wself  = (float*)alloc((size_t)n_nodes * 4 * sizeof(float));
    float*  rden   = (float*)alloc((size_t)n_nodes * 4 * sizeof(float));
    (void)ws_size; (void)n_in; (void)out_size;

    hipMemsetAsync(cursor, 0, (size_t)n_nodes * sizeof(int), stream);

    cvt_wt<<<(HD * IN_F) / 256, 256, 0, stream>>>(W, WT);
    calc_va<<<(HEADS * IN_F) / 256, 256, 0, stream>>>(W, att_src, att_dst, va_s, va_d);
    fused_x<<<(n_nodes + 3) / 4, 256, 0, stream>>>(x, va_s, va_d, Xb, a_s, a_d, n_nodes);
    build_table<<<(n_edges + 255) / 256, 256, 0, stream>>>(src, dst, cursor, table, n_edges);

    dim3 ggrid(HD / GBN, (n_nodes + GBM - 1) / GBM);   // 4 x 235
    gemm_mfma<<<ggrid, 256, 0, stream>>>(Xb, WT, Hb, n_nodes);

    prep_weights<<<(n_nodes + 3) / 4, 256, 0, stream>>>(a_s, a_d, cursor, table,
                                                        wtab, wself, rden, n_nodes);
    gat_agg<<<(n_nodes + 3) / 4, 256, 0, stream>>>(Hb, wtab, wself, rden, cursor, table,
                                                   bias, out);
}

// Round 4
// 229.906 us; speedup vs baseline: 1.6462x; 1.0252x over previous
//
#include <hip/hip_runtime.h>
#include <math.h>

#define IN_F   256
#define OUT_F  128
#define HEADS  4
#define HD     (HEADS * OUT_F)   // 512
#define NEG    0.2f
#define CAP    64                // per-node in-edge capacity (mean deg 16; P(deg>64) ~ 1e-18)

typedef __attribute__((ext_vector_type(8))) short short8;   // 8 bf16 = 4 VGPRs
typedef __attribute__((ext_vector_type(4))) float f32x4;

typedef __attribute__((address_space(1))) const void* gp_t;
typedef __attribute__((address_space(3))) void* lp_t;

static __device__ __forceinline__ ushort f2bf(float f) {
    union { float f; unsigned u; } v; v.f = f;
    unsigned r = (v.u + 0x7FFFu + ((v.u >> 16) & 1u)) >> 16;   // RNE
    return (ushort)r;
}
static __device__ __forceinline__ float bflo(unsigned u) {
    union { unsigned u; float f; } v; v.u = u << 16; return v.f;
}
static __device__ __forceinline__ float bfhi(unsigned u) {
    union { unsigned u; float f; } v; v.u = u & 0xFFFF0000u; return v.f;
}

// ---------------- WT bf16 [512][256] + va = W @ att  (fp32 [4][256] x2) ----------------
__global__ __launch_bounds__(256) void cvt_wt(const float* __restrict__ W,
                                              ushort* __restrict__ WT) {
    int idx = blockIdx.x * blockDim.x + threadIdx.x;   // 512*256
    int n = idx >> 8, k = idx & 255;
    WT[idx] = f2bf(W[k * HD + n]);
}
__global__ __launch_bounds__(256) void calc_va(const float* __restrict__ W,
                                               const float* __restrict__ att_src,
                                               const float* __restrict__ att_dst,
                                               float* __restrict__ va_s,
                                               float* __restrict__ va_d) {
    int idx = blockIdx.x * blockDim.x + threadIdx.x;   // 4*256
    int h = idx >> 8, k = idx & 255;
    const float* wr = W + (size_t)k * HD + h * OUT_F;
    const float* as = att_src + h * OUT_F;
    const float* ad = att_dst + h * OUT_F;
    float ss = 0.f, sd = 0.f;
#pragma unroll 8
    for (int c = 0; c < OUT_F; ++c) {
        float w = wr[c];
        ss = fmaf(w, as[c], ss);
        sd = fmaf(w, ad[c], sd);
    }
    va_s[idx] = ss;
    va_d[idx] = sd;
}

// ------- fused: X f32 -> Xb bf16, plus a_s/a_d = x . va (wave per node) -------
__global__ __launch_bounds__(256) void fused_x(const float* __restrict__ X,
                                               const float* __restrict__ va_s,
                                               const float* __restrict__ va_d,
                                               ushort* __restrict__ Xb,
                                               float* __restrict__ a_s,
                                               float* __restrict__ a_d,
                                               int n_nodes) {
    const int lane = threadIdx.x & 63;
    const int node = blockIdx.x * 4 + (threadIdx.x >> 6);
    if (node >= n_nodes) return;
    float4 v = *(const float4*)(X + (size_t)node * IN_F + lane * 4);
    ushort4 o; o.x = f2bf(v.x); o.y = f2bf(v.y); o.z = f2bf(v.z); o.w = f2bf(v.w);
    *(ushort4*)(Xb + (size_t)node * IN_F + lane * 4) = o;

    float ps[HEADS], pd[HEADS];
#pragma unroll
    for (int hd = 0; hd < HEADS; ++hd) {
        float4 s4 = *(const float4*)(va_s + hd * IN_F + lane * 4);
        float4 d4 = *(const float4*)(va_d + hd * IN_F + lane * 4);
        ps[hd] = v.x * s4.x + v.y * s4.y + v.z * s4.z + v.w * s4.w;
        pd[hd] = v.x * d4.x + v.y * d4.y + v.z * d4.z + v.w * d4.w;
    }
#pragma unroll
    for (int off = 32; off > 0; off >>= 1) {
#pragma unroll
        for (int hd = 0; hd < HEADS; ++hd) {
            ps[hd] += __shfl_xor(ps[hd], off, 64);
            pd[hd] += __shfl_xor(pd[hd], off, 64);
        }
    }
    if (lane == 0) {
        float4 s4 = make_float4(ps[0], ps[1], ps[2], ps[3]);
        float4 d4 = make_float4(pd[0], pd[1], pd[2], pd[3]);
        *(float4*)(a_s + node * 4) = s4;
        *(float4*)(a_d + node * 4) = d4;
    }
}

// ---------------- Hb(bf16) = Xb @ WT^T via bf16 MFMA, global_load_lds staging ----------------
// LDS layout: unpadded 32-ushort rows, chunk slot s holds global chunk s ^ ((row>>1)&3).
// DMA writes lane*16B contiguous (required); fragment ds_read_b128 lands 2-way on banks (free).
#define GBM 128
#define GBN 128
#define GBK 32

__global__ __launch_bounds__(256) void gemm_mfma(const ushort* __restrict__ Xb,
                                                 const ushort* __restrict__ WT,
                                                 ushort* __restrict__ Hb,
                                                 int n_nodes) {
    __shared__ ushort As[GBM][GBK];
    __shared__ ushort Bs[GBN][GBK];
    const int tid = threadIdx.x;
    const int m0 = blockIdx.y * GBM;
    const int n0 = blockIdx.x * GBN;
    const int wave = tid >> 6, lane = tid & 63;
    const int wm = (wave & 1) * 64, wn = (wave >> 1) * 64;
    const int l15 = lane & 15, quad = lane >> 4;

    // staging: wave w covers rows w*16..w*16+15 (and +64); lane -> (row, slot)
    const int rr = lane >> 2;                       // row within strip
    const int cg = (lane & 3) ^ ((lane >> 3) & 3);  // swizzled global chunk
    const int rA = wave * 16 + rr;
    const ushort* gA0 = Xb + (size_t)(m0 + rA) * IN_F + cg * 8;
    const ushort* gA1 = Xb + (size_t)(m0 + 64 + rA) * IN_F + cg * 8;
    const ushort* gB0 = WT + (size_t)(n0 + rA) * IN_F + cg * 8;
    const ushort* gB1 = WT + (size_t)(n0 + 64 + rA) * IN_F + cg * 8;
    ushort* lA0 = &As[wave * 16][0];
    ushort* lA1 = &As[64 + wave * 16][0];
    ushort* lB0 = &Bs[wave * 16][0];
    ushort* lB1 = &Bs[64 + wave * 16][0];

    f32x4 acc[4][4];
#pragma unroll
    for (int i = 0; i < 4; ++i)
#pragma unroll
        for (int j = 0; j < 4; ++j) acc[i][j] = (f32x4){0.f, 0.f, 0.f, 0.f};

    const int ks = (quad ^ ((l15 >> 1) & 3)) * 8;   // swizzled fragment k-offset

    for (int k0 = 0; k0 < IN_F; k0 += GBK) {
        __syncthreads();
        __builtin_amdgcn_global_load_lds((gp_t)(gA0 + k0), (lp_t)lA0, 16, 0, 0);
        __builtin_amdgcn_global_load_lds((gp_t)(gA1 + k0), (lp_t)lA1, 16, 0, 0);
        __builtin_amdgcn_global_load_lds((gp_t)(gB0 + k0), (lp_t)lB0, 16, 0, 0);
        __builtin_amdgcn_global_load_lds((gp_t)(gB1 + k0), (lp_t)lB1, 16, 0, 0);
        __syncthreads();

        short8 af[4], bf_[4];
#pragma unroll
        for (int f = 0; f < 4; ++f) {
            af[f]  = *(const short8*)&As[wm + f * 16 + l15][ks];
            bf_[f] = *(const short8*)&Bs[wn + f * 16 + l15][ks];
        }
#pragma unroll
        for (int fm = 0; fm < 4; ++fm)
#pragma unroll
            for (int fn = 0; fn < 4; ++fn)
                acc[fm][fn] = __builtin_amdgcn_mfma_f32_16x16x32_bf16(
                    af[fm], bf_[fn], acc[fm][fn], 0, 0, 0);
    }

#pragma unroll
    for (int fm = 0; fm < 4; ++fm) {
        int gmb = m0 + wm + fm * 16 + quad * 4;
#pragma unroll
        for (int reg = 0; reg < 4; ++reg) {
            int gm = gmb + reg;
            if (gm < n_nodes) {
#pragma unroll
                for (int fn = 0; fn < 4; ++fn)
                    Hb[(size_t)gm * HD + n0 + wn + fn * 16 + l15] =
                        f2bf(acc[fm][fn][reg]);
            }
        }
    }
}

// --------- bucket edges by dst: table[d][r] = src ---------
__global__ __launch_bounds__(256) void build_table(const int* __restrict__ src,
                                                   const int* __restrict__ dst,
                                                   int* __restrict__ cursor,
                                                   int* __restrict__ table,
                                                   int n_edges) {
    int e = blockIdx.x * blockDim.x + threadIdx.x;
    if (e >= n_edges) return;
    int d = dst[e];
    int r = atomicAdd(&cursor[d], 1);
    if (r < CAP) table[(size_t)d * CAP + r] = src[e];
}

// --------- fused softmax + aggregation: wave per node ---------
// lane-per-edge softmax (butterfly), then agg loop with weights via shuffle broadcast;
// lane owns 2 channels x 4 heads (bf16 pairs).
__global__ __launch_bounds__(256) void gat_agg(const ushort* __restrict__ Hb,
                                               const float* __restrict__ a_s,
                                               const float* __restrict__ a_d,
                                               const int* __restrict__ cursor,
                                               const int* __restrict__ table,
                                               const float* __restrict__ bias,
                                               float* __restrict__ out,
                                               int n_nodes) {
    const int lane = threadIdx.x & 63;
    const int n = blockIdx.x * 4 + (threadIdx.x >> 6);
    if (n >= n_nodes) return;
    int deg = cursor[n]; if (deg > CAP) deg = CAP;
    const int* row = table + (size_t)n * CAP;
    const unsigned* hbase = (const unsigned*)Hb;

    // ---- softmax over self + in-edges (lane e owns edge e) ----
    const float4 ad4 = *(const float4*)(a_d + n * 4);
    const float4 as4 = *(const float4*)(a_s + n * 4);
    const float ad[4] = {ad4.x, ad4.y, ad4.z, ad4.w};
    float aself[4];
    {
        const float asn[4] = {as4.x, as4.y, as4.z, as4.w};
#pragma unroll
        for (int hd = 0; hd < 4; ++hd) {
            float al = asn[hd] + ad[hd];
            aself[hd] = al > 0.f ? al : NEG * al;
        }
    }
    const bool act = lane < deg;
    float al[4];
    {
        int s = act ? row[lane] : 0;
        float4 av = *(const float4*)(a_s + s * 4);
        const float as_[4] = {av.x, av.y, av.z, av.w};
#pragma unroll
        for (int hd = 0; hd < 4; ++hd) {
            float a = as_[hd] + ad[hd];
            a = a > 0.f ? a : NEG * a;
            al[hd] = act ? a : -1e30f;
        }
    }
    float m[4];
#pragma unroll
    for (int hd = 0; hd < 4; ++hd) m[hd] = al[hd];
#pragma unroll
    for (int off = 32; off > 0; off >>= 1)
#pragma unroll
        for (int hd = 0; hd < 4; ++hd)
            m[hd] = fmaxf(m[hd], __shfl_xor(m[hd], off, 64));
#pragma unroll
    for (int hd = 0; hd < 4; ++hd) m[hd] = fmaxf(m[hd], aself[hd]);

    float w[4], den[4], es[4];
#pragma unroll
    for (int hd = 0; hd < 4; ++hd) {
        w[hd] = act ? __expf(al[hd] - m[hd]) : 0.f;
        den[hd] = w[hd];
    }
#pragma unroll
    for (int off = 32; off > 0; off >>= 1)
#pragma unroll
        for (int hd = 0; hd < 4; ++hd)
            den[hd] += __shfl_xor(den[hd], off, 64);
    float rdv[4];
#pragma unroll
    for (int hd = 0; hd < 4; ++hd) {
        es[hd] = __expf(aself[hd] - m[hd]);
        rdv[hd] = 1.f / (den[hd] + es[hd]);
    }

    // ---- aggregation ----
    float acc0[4], acc1[4];
    {
        const unsigned* p = hbase + (size_t)n * 256;
#pragma unroll
        for (int hd = 0; hd < 4; ++hd) {
            unsigned u = p[hd * 64 + lane];
            acc0[hd] = es[hd] * bflo(u);
            acc1[hd] = es[hd] * bfhi(u);
        }
    }
    int e = 0;
    for (; e + 8 <= deg; e += 8) {
        int4 ra = *(const int4*)(row + e);
        int4 rb = *(const int4*)(row + e + 4);
        const unsigned* p[8];
        p[0] = hbase + (size_t)ra.x * 256; p[1] = hbase + (size_t)ra.y * 256;
        p[2] = hbase + (size_t)ra.z * 256; p[3] = hbase + (size_t)ra.w * 256;
        p[4] = hbase + (size_t)rb.x * 256; p[5] = hbase + (size_t)rb.y * 256;
        p[6] = hbase + (size_t)rb.z * 256; p[7] = hbase + (size_t)rb.w * 256;
        unsigned u[8][4];
#pragma unroll
        for (int j = 0; j < 8; ++j)
#pragma unroll
            for (int hd = 0; hd < 4; ++hd)
                u[j][hd] = p[j][hd * 64 + lane];
#pragma unroll
        for (int j = 0; j < 8; ++j) {
#pragma unroll
            for (int hd = 0; hd < 4; ++hd) {
                float wv = __shfl(w[hd], e + j, 64);
                acc0[hd] = fmaf(wv, bflo(u[j][hd]), acc0[hd]);
                acc1[hd] = fmaf(wv, bfhi(u[j][hd]), acc1[hd]);
            }
        }
    }
    for (; e < deg; ++e) {
        int s = row[e];
        const unsigned* p = hbase + (size_t)s * 256;
#pragma unroll
        for (int hd = 0; hd < 4; ++hd) {
            unsigned u = p[hd * 64 + lane];
            float wv = __shfl(w[hd], e, 64);
            acc0[hd] = fmaf(wv, bflo(u), acc0[hd]);
            acc1[hd] = fmaf(wv, bfhi(u), acc1[hd]);
        }
    }
    float o0 = 0.f, o1 = 0.f;
#pragma unroll
    for (int hd = 0; hd < 4; ++hd) {
        o0 = fmaf(acc0[hd], rdv[hd], o0);
        o1 = fmaf(acc1[hd], rdv[hd], o1);
    }
    float2 b = *(const float2*)(bias + 2 * lane);
    o0 = 0.25f * o0 + b.x;
    o1 = 0.25f * o1 + b.y;
    float2 ov = make_float2(tanhf(o0), tanhf(o1));
    *(float2*)(out + (size_t)n * OUT_F + 2 * lane) = ov;
}

extern "C" void kernel_launch(void* const* d_in, const int* in_sizes, int n_in,
                              void* d_out, int out_size, void* d_ws, size_t ws_size,
                              hipStream_t stream) {
    const float* x       = (const float*)d_in[0];
    const int*   ei      = (const int*)d_in[1];
    const float* W       = (const float*)d_in[2];
    const float* att_src = (const float*)d_in[3];
    const float* att_dst = (const float*)d_in[4];
    const float* bias    = (const float*)d_in[5];
    float* out = (float*)d_out;

    const int n_nodes = in_sizes[0] / IN_F;     // 30000
    const int n_edges = in_sizes[1] / 2;        // 480000
    const int* src = ei;
    const int* dst = ei + n_edges;

    char* ws = (char*)d_ws;
    size_t off = 0;
    auto alloc = [&](size_t bytes) -> void* {
        void* p = ws + off;
        off = (off + bytes + 255) & ~(size_t)255;
        return p;
    };
    ushort* Xb     = (ushort*)alloc((size_t)n_nodes * IN_F * sizeof(ushort));   // 15.4 MB
    ushort* Hb     = (ushort*)alloc((size_t)n_nodes * HD * sizeof(ushort));     // 30.7 MB
    ushort* WT     = (ushort*)alloc((size_t)HD * IN_F * sizeof(ushort));        // 0.26 MB
    float*  va_s   = (float*)alloc((size_t)HEADS * IN_F * sizeof(float));
    float*  va_d   = (float*)alloc((size_t)HEADS * IN_F * sizeof(float));
    float*  a_s    = (float*)alloc((size_t)n_nodes * HEADS * sizeof(float));
    float*  a_d    = (float*)alloc((size_t)n_nodes * HEADS * sizeof(float));
    int*    cursor = (int*)alloc((size_t)n_nodes * sizeof(int));
    int*    table  = (int*)alloc((size_t)n_nodes * CAP * sizeof(int));          // 7.7 MB
    (void)ws_size; (void)n_in; (void)out_size;

    hipMemsetAsync(cursor, 0, (size_t)n_nodes * sizeof(int), stream);

    cvt_wt<<<(HD * IN_F) / 256, 256, 0, stream>>>(W, WT);
    calc_va<<<(HEADS * IN_F) / 256, 256, 0, stream>>>(W, att_src, att_dst, va_s, va_d);
    fused_x<<<(n_nodes + 3) / 4, 256, 0, stream>>>(x, va_s, va_d, Xb, a_s, a_d, n_nodes);
    build_table<<<(n_edges + 255) / 256, 256, 0, stream>>>(src, dst, cursor, table, n_edges);

    dim3 ggrid(HD / GBN, (n_nodes + GBM - 1) / GBM);   // 4 x 235
    gemm_mfma<<<ggrid, 256, 0, stream>>>(Xb, WT, Hb, n_nodes);

    gat_agg<<<(n_nodes + 3) / 4, 256, 0, stream>>>(Hb, a_s, a_d, cursor, table,
                                                   bias, out, n_nodes);
}